// Round 1
// baseline (1109.794 us; speedup 1.0000x reference)
//
#include <hip/hip_runtime.h>
#include <math.h>

#define NS   16
#define CIN  3
#define CF   32
#define CROP 256
#define KH   129   // CROP/2 + 1

#define TWO_PI_OVER_256 0.0245436926f

// ---------------------------------------------------------------------------
// Kernel 1: fused conv1+ReLU -> conv2 -> LRN -> *cos_window -> sum over C
// one block = 16x16 output tile of one sample. 256 threads.
// LDS: f1 halo tile [32][18][18] fp32 + w2 reordered [ci][k9][co]  (~78 KB)
// ---------------------------------------------------------------------------
__global__ __launch_bounds__(256, 2)
void fused_features(const float* __restrict__ z,
                    const float* __restrict__ w1,
                    const float* __restrict__ b1,
                    const float* __restrict__ w2,
                    const float* __restrict__ b2,
                    const float* __restrict__ cosw,
                    float* __restrict__ g)
{
    __shared__ __align__(16) float s_f1[CF * 18 * 18];   // 10368 floats
    __shared__ __align__(16) float s_w2[CF * 9 * CF];    //  9216 floats [ci][k9][co]

    // stage-1 temporaries alias the (not-yet-loaded) w2 region
    float* zt  = s_w2;           // 3*20*20 = 1200 floats
    float* w1s = s_w2 + 1200;    // 864 floats

    const int tid = threadIdx.x;
    const int n  = blockIdx.z;
    const int bx = blockIdx.x, by = blockIdx.y;

    // ---- stage 1: load z tile (3 x 20 x 20), zero padded ----
    const int zy0 = by * 16 - 2;
    const int zx0 = bx * 16 - 2;
    for (int idx = tid; idx < CIN * 400; idx += 256) {
        int ci = idx / 400;
        int r  = idx - ci * 400;
        int yy = r / 20, xx = r - yy * 20;
        int gy = zy0 + yy, gx = zx0 + xx;
        float v = 0.0f;
        if (gy >= 0 && gy < CROP && gx >= 0 && gx < CROP)
            v = z[((n * CIN + ci) * CROP + gy) * CROP + gx];
        zt[idx] = v;
    }
    for (int idx = tid; idx < CF * CIN * 9; idx += 256)
        w1s[idx] = w1[idx];
    __syncthreads();

    // ---- stage 2: f1 = relu(conv1) on 18x18 halo tile; zero outside image
    //      (conv2's SAME padding requires f1==0 outside [0,256)) ----
    const int fy0 = by * 16 - 1;
    const int fx0 = bx * 16 - 1;
    for (int idx = tid; idx < CF * 324; idx += 256) {
        int co = idx / 324;
        int r  = idx - co * 324;
        int y  = r / 18, x = r - y * 18;
        int gy = fy0 + y, gx = fx0 + x;
        float v = 0.0f;
        if (gy >= 0 && gy < CROP && gx >= 0 && gx < CROP) {
            float acc = b1[co];
            #pragma unroll
            for (int ci = 0; ci < CIN; ++ci)
                #pragma unroll
                for (int ky = 0; ky < 3; ++ky)
                    #pragma unroll
                    for (int kx = 0; kx < 3; ++kx)
                        acc += zt[ci * 400 + (y + ky) * 20 + (x + kx)]
                             * w1s[(co * CIN + ci) * 9 + ky * 3 + kx];
            v = fmaxf(acc, 0.0f);
        }
        s_f1[idx] = v;
    }
    __syncthreads();

    // ---- stage 3a: load w2 reordered to [ci][k9][co] (overwrites zt/w1s) ----
    for (int idx = tid; idx < CF * 9 * CF; idx += 256) {
        int ci = idx / 288;
        int r  = idx - ci * 288;
        int k9 = r / 32, co = r - k9 * 32;
        s_w2[idx] = w2[(co * CF + ci) * 9 + k9];
    }
    __syncthreads();

    // ---- stage 3b: conv2 (one pixel per thread, all 32 output channels) ----
    const int tx = tid & 15, ty = tid >> 4;
    float acc[CF];
    #pragma unroll
    for (int co = 0; co < CF; ++co) acc[co] = b2[co];

    for (int ci = 0; ci < CF; ++ci) {
        #pragma unroll
        for (int k9 = 0; k9 < 9; ++k9) {
            const int ky = k9 / 3, kx = k9 - ky * 3;
            float v = s_f1[ci * 324 + (ty + ky) * 18 + (tx + kx)];
            const float* wrow = &s_w2[(ci * 9 + k9) * CF];
            #pragma unroll
            for (int c4 = 0; c4 < CF; c4 += 4) {
                float4 w4 = *(const float4*)&wrow[c4];   // broadcast ds_read_b128
                acc[c4]     = fmaf(v, w4.x, acc[c4]);
                acc[c4 + 1] = fmaf(v, w4.y, acc[c4 + 1]);
                acc[c4 + 2] = fmaf(v, w4.z, acc[c4 + 2]);
                acc[c4 + 3] = fmaf(v, w4.w, acc[c4 + 3]);
            }
        }
    }

    // ---- LRN(size=5, alpha=1e-4, beta=0.75, k=1) + cos window + channel sum
    float s = 0.0f;
    #pragma unroll
    for (int c = 0; c < CF; ++c) {
        float win = 0.0f;
        #pragma unroll
        for (int j = c - 2; j <= c + 2; ++j)
            if (j >= 0 && j < CF) win += acc[j] * acc[j];
        float base = 1.0f + 2e-5f * win;      // alpha/size = 1e-4/5
        s += acc[c] * __powf(base, -0.75f);
    }
    const int gy = by * 16 + ty, gx = bx * 16 + tx;
    g[(n * CROP + gy) * CROP + gx] = s * cosw[gy * CROP + gx];
}

// ---------------------------------------------------------------------------
// Kernel 2: rfft along last axis. one block = one (n,y) row.
// zr[k] =  sum_x g[x] cos(2*pi*k*x/256)
// zi[k] = -sum_x g[x] sin(2*pi*k*x/256)          (numpy rfft sign convention)
// ---------------------------------------------------------------------------
__global__ __launch_bounds__(256)
void dft_row(const float* __restrict__ g,
             float* __restrict__ zr, float* __restrict__ zi)
{
    __shared__ float row[256], ct[256], st[256];
    const int b = blockIdx.x;          // n*256 + y
    const int t = threadIdx.x;

    { float s, c; sincosf(TWO_PI_OVER_256 * (float)t, &s, &c); ct[t] = c; st[t] = s; }
    row[t] = g[b * 256 + t];
    __syncthreads();

    if (t < KH) {
        float ar = 0.0f, ai = 0.0f;
        int idx = 0;
        for (int x = 0; x < 256; ++x) {
            float v = row[x];
            ar += v * ct[idx];
            ai -= v * st[idx];
            idx = (idx + t) & 255;
        }
        zr[b * KH + t] = ar;
        zi[b * KH + t] = ai;
    }
}

// ---------------------------------------------------------------------------
// Kernel 3: fft along axis -2, multiply by wc = wf[0,1,:,:,0] - i*wf[0,1,:,:,1],
// then ifft along axis -2 (with 1/256). one block = one (n,k) column.
// ---------------------------------------------------------------------------
__global__ __launch_bounds__(256)
void dft_col_mul_inv(const float* __restrict__ zr, const float* __restrict__ zi,
                     const float* __restrict__ wf,
                     float* __restrict__ br, float* __restrict__ bi)
{
    __shared__ float cr[256], cis[256], fr[256], fi[256], ct[256], st[256];
    const int b = blockIdx.x;          // n*129 + k
    const int n = b / KH, k = b - n * KH;
    const int t = threadIdx.x;

    { float s, c; sincosf(TWO_PI_OVER_256 * (float)t, &s, &c); ct[t] = c; st[t] = s; }
    cr[t]  = zr[(n * 256 + t) * KH + k];
    cis[t] = zi[(n * 256 + t) * KH + k];
    __syncthreads();

    // forward fft over y (t = m):  e^{-i theta}
    float ar = 0.0f, ai = 0.0f;
    int idx = 0;
    for (int y = 0; y < 256; ++y) {
        float c = ct[idx], s = st[idx];
        ar += cr[y] * c + cis[y] * s;
        ai += cis[y] * c - cr[y] * s;
        idx = (idx + t) & 255;
    }
    const float wr  = wf[((256 + t) * KH + k) * 2];
    const float wfi = wf[((256 + t) * KH + k) * 2 + 1];
    fr[t] = wr * ar + wfi * ai;        // (wr - i*wfi) * (ar + i*ai)
    fi[t] = wr * ai - wfi * ar;
    __syncthreads();

    // inverse fft over m (t = y):  e^{+i theta}, scale 1/256
    ar = 0.0f; ai = 0.0f;
    idx = 0;
    for (int m = 0; m < 256; ++m) {
        float c = ct[idx], s = st[idx];
        ar += fr[m] * c - fi[m] * s;
        ai += fr[m] * s + fi[m] * c;
        idx = (idx + t) & 255;
    }
    br[(n * 256 + t) * KH + k] = ar * (1.0f / 256.0f);
    bi[(n * 256 + t) * KH + k] = ai * (1.0f / 256.0f);
}

// ---------------------------------------------------------------------------
// Kernel 4: irfft along last axis (129 -> 256), scale 1/256.
// out[x] = (1/256) * [ B0.re + 2*sum_{k=1..127}(Bk.re*cos - Bk.im*sin)
//                      + B128.re*(-1)^x ]
// ---------------------------------------------------------------------------
__global__ __launch_bounds__(256)
void idft_row(const float* __restrict__ br, const float* __restrict__ bi,
              float* __restrict__ out)
{
    __shared__ float rr[KH], ri[KH], ct[256], st[256];
    const int b = blockIdx.x;          // n*256 + y
    const int t = threadIdx.x;         // x

    { float s, c; sincosf(TWO_PI_OVER_256 * (float)t, &s, &c); ct[t] = c; st[t] = s; }
    if (t < KH) { rr[t] = br[b * KH + t]; ri[t] = bi[b * KH + t]; }
    __syncthreads();

    float acc = rr[0];                 // k = 0 term (imag dropped)
    int idx = t;                       // (k*x)&255 at k=1
    for (int k = 1; k < 128; ++k) {
        acc += 2.0f * (rr[k] * ct[idx] - ri[k] * st[idx]);
        idx = (idx + t) & 255;
    }
    acc += rr[128] * ct[idx] - ri[128] * st[idx];   // k = 128 (st ~ 0)
    out[b * 256 + t] = acc * (1.0f / 256.0f);
}

// ---------------------------------------------------------------------------
extern "C" void kernel_launch(void* const* d_in, const int* in_sizes, int n_in,
                              void* d_out, int out_size, void* d_ws, size_t ws_size,
                              hipStream_t stream)
{
    const float* z    = (const float*)d_in[0];
    const float* w1   = (const float*)d_in[1];
    const float* b1   = (const float*)d_in[2];
    const float* w2   = (const float*)d_in[3];
    const float* b2   = (const float*)d_in[4];
    const float* cosw = (const float*)d_in[5];
    const float* wf   = (const float*)d_in[6];
    float* out = (float*)d_out;

    // workspace layout (floats): g | zr | zi | br | bi   (~12.6 MB total)
    float* g  = (float*)d_ws;
    float* zr = g  + NS * CROP * CROP;
    float* zi = zr + NS * CROP * KH;
    float* br = zi + NS * CROP * KH;
    float* bi = br + NS * CROP * KH;

    fused_features<<<dim3(16, 16, NS), 256, 0, stream>>>(z, w1, b1, w2, b2, cosw, g);
    dft_row<<<NS * CROP, 256, 0, stream>>>(g, zr, zi);
    dft_col_mul_inv<<<NS * KH, 256, 0, stream>>>(zr, zi, wf, br, bi);
    idft_row<<<NS * CROP, 256, 0, stream>>>(br, bi, out);
}

// Round 2
// 389.219 us; speedup vs baseline: 2.8513x; 2.8513x over previous
//
#include <hip/hip_runtime.h>
#include <math.h>

#define NS   16
#define CIN  3
#define CF   32
#define CROP 256
#define KH   129   // CROP/2 + 1

#define TWO_PI_OVER_256 0.0245436926f

typedef _Float16 half8 __attribute__((ext_vector_type(8)));
typedef float    f32x4 __attribute__((ext_vector_type(4)));

// LDS layout (bytes):
//   [0,     21504)  X : zim / f1t  [336 pixels][32 k] f16, slot-swizzled
//   [21504, 39936)  W : w2 as [k9][co][ci] f16, slot-swizzled
//   [39936, 44736)  Z : z tile [3][20][20] f32
//   epilogue reuses [0, 36864) as E : [256 pixels][36] f32
#define X_OFF 0
#define W_OFF 21504
#define Z_OFF 39936
#define LDS_BYTES 44736

// byte address of (pixel q, 16B slot s) in X; swizzle keeps b128 reads minimal-phase
__device__ __forceinline__ int xaddr(int q, int s) {
    return X_OFF + (q << 6) + ((s ^ ((q >> 1) & 3)) << 4);
}
__device__ __forceinline__ int waddr(int k9, int co, int s) {
    return W_OFF + (((k9 << 5) + co) << 6) + ((s ^ ((co >> 1) & 3)) << 4);
}

// ---------------------------------------------------------------------------
// Kernel 1: fused conv1+ReLU -> conv2 -> LRN -> *cos_window -> sum over C
// one block = 16x16 output tile. 256 threads = 4 waves.
// conv1: MFMA over im2col K=27(pad 32); conv2: 9 x MFMA GEMMs K=32 (channels)
// ---------------------------------------------------------------------------
__global__ __launch_bounds__(256, 2)
void fused_features(const float* __restrict__ z,
                    const float* __restrict__ w1,
                    const float* __restrict__ b1,
                    const float* __restrict__ w2,
                    const float* __restrict__ b2,
                    const float* __restrict__ cosw,
                    float* __restrict__ g)
{
    __shared__ __align__(16) unsigned char smem[LDS_BYTES];
    float* ztile = (float*)(smem + Z_OFF);

    const int tid  = threadIdx.x;
    const int lane = tid & 63;
    const int wv   = tid >> 6;
    const int l15  = lane & 15;
    const int lhi  = lane >> 4;      // 0..3 = k-group / row-group selector

    const int n  = blockIdx.z;
    const int bx = blockIdx.x, by = blockIdx.y;
    const int fy0 = by * 16 - 1;     // f1-halo origin (18x18)
    const int fx0 = bx * 16 - 1;

    // ---- stage z tile (3 x 20 x 20), zero padded ----
    const int zy0 = by * 16 - 2;
    const int zx0 = bx * 16 - 2;
    for (int idx = tid; idx < CIN * 400; idx += 256) {
        int ci = idx / 400;
        int r  = idx - ci * 400;
        int yy = r / 20, xx = r - yy * 20;
        int gy = zy0 + yy, gx = zx0 + xx;
        float v = 0.0f;
        if ((unsigned)gy < CROP && (unsigned)gx < CROP)
            v = z[((n * CIN + ci) * CROP + gy) * CROP + gx];
        ztile[idx] = v;
    }

    // ---- conv1 weight fragments + biases (global gather, once per block) ----
    half8 w1f[2];
    #pragma unroll
    for (int cg = 0; cg < 2; ++cg) {
        int co = cg * 16 + l15;
        #pragma unroll
        for (int j = 0; j < 8; ++j) {
            int k = lhi * 8 + j;                      // k = ci*9 + ky*3 + kx
            w1f[cg][j] = (k < 27) ? (_Float16)w1[co * 27 + k] : (_Float16)0.f;
        }
    }
    float bias1[2] = { b1[l15], b1[16 + l15] };
    float bias2[2] = { b2[l15], b2[16 + l15] };

    __syncthreads();

    // ---- build zim: im2col of f1-halo pixels, [324][32] f16 (k-pad zeroed) ----
    for (int q = tid; q < 324; q += 256) {
        int y = q / 18, x = q - y * 18;
        const float* zb = ztile + y * 20 + x;
        _Float16 v[32];
        #pragma unroll
        for (int ci = 0; ci < 3; ++ci)
            #pragma unroll
            for (int ky = 0; ky < 3; ++ky)
                #pragma unroll
                for (int kx = 0; kx < 3; ++kx)
                    v[ci * 9 + ky * 3 + kx] = (_Float16)zb[ci * 400 + ky * 20 + kx];
        #pragma unroll
        for (int k = 27; k < 32; ++k) v[k] = (_Float16)0.f;
        #pragma unroll
        for (int s = 0; s < 4; ++s) {
            half8 h;
            #pragma unroll
            for (int j = 0; j < 8; ++j) h[j] = v[s * 8 + j];
            *(half8*)(smem + xaddr(q, s)) = h;
        }
    }

    // ---- stage w2 into LDS as [k9][co][ci] f16 (slot-swizzled) ----
    for (int idx = tid; idx < CF * CF * 9; idx += 256) {
        int co = idx / 288;
        int r  = idx - co * 288;
        int ci = r / 9, k9 = r - ci * 9;
        *(_Float16*)(smem + waddr(k9, co, ci >> 3) + ((ci & 7) << 1)) =
            (_Float16)w2[idx];
    }
    __syncthreads();

    // ---- conv1 via MFMA, in place (each wave owns disjoint pixel row-tiles) ----
    const f32x4 zero4 = {0.f, 0.f, 0.f, 0.f};
    for (int t = wv; t < 21; t += 4) {
        int qa = t * 16 + l15;
        half8 a = *(const half8*)(smem + xaddr(qa, lhi));
        f32x4 d0 = __builtin_amdgcn_mfma_f32_16x16x32_f16(a, w1f[0], zero4, 0, 0, 0);
        f32x4 d1 = __builtin_amdgcn_mfma_f32_16x16x32_f16(a, w1f[1], zero4, 0, 0, 0);
        #pragma unroll
        for (int r = 0; r < 4; ++r) {
            int qq = t * 16 + lhi * 4 + r;
            int y = qq / 18, x = qq - y * 18;
            int gy = fy0 + y, gx = fx0 + x;
            bool ok = ((unsigned)gy < CROP) && ((unsigned)gx < CROP) && (qq < 324);
            float v0 = ok ? fmaxf(d0[r] + bias1[0], 0.f) : 0.f;
            float v1 = ok ? fmaxf(d1[r] + bias1[1], 0.f) : 0.f;
            int sw = (qq >> 1) & 3;
            int c0 = l15, c1 = 16 + l15;
            *(_Float16*)(smem + X_OFF + (qq << 6) + (((c0 >> 3) ^ sw) << 4) + ((c0 & 7) << 1)) = (_Float16)v0;
            *(_Float16*)(smem + X_OFF + (qq << 6) + (((c1 >> 3) ^ sw) << 4) + ((c1 & 7) << 1)) = (_Float16)v1;
        }
    }
    __syncthreads();

    // ---- conv2 via MFMA: 9 shifted GEMMs over K=32 channels ----
    f32x4 acc[4][2];
    #pragma unroll
    for (int tt = 0; tt < 4; ++tt)
        #pragma unroll
        for (int cg = 0; cg < 2; ++cg)
            acc[tt][cg] = (f32x4){bias2[cg], bias2[cg], bias2[cg], bias2[cg]};

    #pragma unroll
    for (int k9 = 0; k9 < 9; ++k9) {
        const int ky = k9 / 3, kx = k9 - 3 * (k9 / 3);
        half8 b0 = *(const half8*)(smem + waddr(k9, l15,      lhi));
        half8 b1 = *(const half8*)(smem + waddr(k9, l15 + 16, lhi));
        #pragma unroll
        for (int tt = 0; tt < 4; ++tt) {
            int py = wv * 4 + tt;                     // output pixel row
            int q  = (py + ky) * 18 + l15 + kx;       // f1-halo pixel
            half8 a = *(const half8*)(smem + xaddr(q, lhi));
            acc[tt][0] = __builtin_amdgcn_mfma_f32_16x16x32_f16(a, b0, acc[tt][0], 0, 0, 0);
            acc[tt][1] = __builtin_amdgcn_mfma_f32_16x16x32_f16(a, b1, acc[tt][1], 0, 0, 0);
        }
    }
    __syncthreads();                                  // all X/W reads done

    // ---- dump acc to E [256][36] f32 (row stride 144B -> conflict-free b128) ----
    float* E = (float*)smem;
    #pragma unroll
    for (int tt = 0; tt < 4; ++tt)
        #pragma unroll
        for (int cg = 0; cg < 2; ++cg)
            #pragma unroll
            for (int r = 0; r < 4; ++r) {
                int p  = (wv * 4 + tt) * 16 + lhi * 4 + r;
                int co = cg * 16 + l15;
                E[p * 36 + co] = acc[tt][cg][r];
            }
    __syncthreads();

    // ---- LRN(5, 1e-4, 0.75, 1) + cos window + channel sum; one pixel/thread ----
    {
        const float* row = E + tid * 36;
        float a2[CF];
        #pragma unroll
        for (int c = 0; c < CF; ++c) a2[c] = row[c];
        float s = 0.0f;
        #pragma unroll
        for (int c = 0; c < CF; ++c) {
            float win = 0.0f;
            #pragma unroll
            for (int j = c - 2; j <= c + 2; ++j)
                if (j >= 0 && j < CF) win += a2[j] * a2[j];
            float base = 1.0f + 2e-5f * win;          // alpha/size = 1e-4/5
            s += a2[c] * __powf(base, -0.75f);
        }
        const int ty = tid >> 4, tx = tid & 15;
        const int gy = by * 16 + ty, gx = bx * 16 + tx;
        g[(n * CROP + gy) * CROP + gx] = s * cosw[gy * CROP + gx];
    }
}

// ---------------------------------------------------------------------------
// Kernel 2: rfft along last axis. one block = one (n,y) row.
// ---------------------------------------------------------------------------
__global__ __launch_bounds__(256)
void dft_row(const float* __restrict__ g,
             float* __restrict__ zr, float* __restrict__ zi)
{
    __shared__ float row[256], ct[256], st[256];
    const int b = blockIdx.x;          // n*256 + y
    const int t = threadIdx.x;

    { float s, c; sincosf(TWO_PI_OVER_256 * (float)t, &s, &c); ct[t] = c; st[t] = s; }
    row[t] = g[b * 256 + t];
    __syncthreads();

    if (t < KH) {
        float ar = 0.0f, ai = 0.0f;
        int idx = 0;
        for (int x = 0; x < 256; ++x) {
            float v = row[x];
            ar += v * ct[idx];
            ai -= v * st[idx];
            idx = (idx + t) & 255;
        }
        zr[b * KH + t] = ar;
        zi[b * KH + t] = ai;
    }
}

// ---------------------------------------------------------------------------
// Kernel 3: fft along axis -2, * conj(wf[0,1]), ifft along axis -2 (1/256)
// ---------------------------------------------------------------------------
__global__ __launch_bounds__(256)
void dft_col_mul_inv(const float* __restrict__ zr, const float* __restrict__ zi,
                     const float* __restrict__ wf,
                     float* __restrict__ br, float* __restrict__ bi)
{
    __shared__ float cr[256], cis[256], fr[256], fi[256], ct[256], st[256];
    const int b = blockIdx.x;          // n*129 + k
    const int n = b / KH, k = b - n * KH;
    const int t = threadIdx.x;

    { float s, c; sincosf(TWO_PI_OVER_256 * (float)t, &s, &c); ct[t] = c; st[t] = s; }
    cr[t]  = zr[(n * 256 + t) * KH + k];
    cis[t] = zi[(n * 256 + t) * KH + k];
    __syncthreads();

    float ar = 0.0f, ai = 0.0f;
    int idx = 0;
    for (int y = 0; y < 256; ++y) {
        float c = ct[idx], s = st[idx];
        ar += cr[y] * c + cis[y] * s;
        ai += cis[y] * c - cr[y] * s;
        idx = (idx + t) & 255;
    }
    const float wr  = wf[((256 + t) * KH + k) * 2];
    const float wfi = wf[((256 + t) * KH + k) * 2 + 1];
    fr[t] = wr * ar + wfi * ai;
    fi[t] = wr * ai - wfi * ar;
    __syncthreads();

    ar = 0.0f; ai = 0.0f;
    idx = 0;
    for (int m = 0; m < 256; ++m) {
        float c = ct[idx], s = st[idx];
        ar += fr[m] * c - fi[m] * s;
        ai += fr[m] * s + fi[m] * c;
        idx = (idx + t) & 255;
    }
    br[(n * 256 + t) * KH + k] = ar * (1.0f / 256.0f);
    bi[(n * 256 + t) * KH + k] = ai * (1.0f / 256.0f);
}

// ---------------------------------------------------------------------------
// Kernel 4: irfft along last axis (129 -> 256), scale 1/256.
// ---------------------------------------------------------------------------
__global__ __launch_bounds__(256)
void idft_row(const float* __restrict__ br, const float* __restrict__ bi,
              float* __restrict__ out)
{
    __shared__ float rr[KH], ri[KH], ct[256], st[256];
    const int b = blockIdx.x;          // n*256 + y
    const int t = threadIdx.x;         // x

    { float s, c; sincosf(TWO_PI_OVER_256 * (float)t, &s, &c); ct[t] = c; st[t] = s; }
    if (t < KH) { rr[t] = br[b * KH + t]; ri[t] = bi[b * KH + t]; }
    __syncthreads();

    float acc = rr[0];
    int idx = t;
    for (int k = 1; k < 128; ++k) {
        acc += 2.0f * (rr[k] * ct[idx] - ri[k] * st[idx]);
        idx = (idx + t) & 255;
    }
    acc += rr[128] * ct[idx] - ri[128] * st[idx];
    out[b * 256 + t] = acc * (1.0f / 256.0f);
}

// ---------------------------------------------------------------------------
extern "C" void kernel_launch(void* const* d_in, const int* in_sizes, int n_in,
                              void* d_out, int out_size, void* d_ws, size_t ws_size,
                              hipStream_t stream)
{
    const float* z    = (const float*)d_in[0];
    const float* w1   = (const float*)d_in[1];
    const float* b1   = (const float*)d_in[2];
    const float* w2   = (const float*)d_in[3];
    const float* b2   = (const float*)d_in[4];
    const float* cosw = (const float*)d_in[5];
    const float* wf   = (const float*)d_in[6];
    float* out = (float*)d_out;

    float* g  = (float*)d_ws;
    float* zr = g  + NS * CROP * CROP;
    float* zi = zr + NS * CROP * KH;
    float* br = zi + NS * CROP * KH;
    float* bi = br + NS * CROP * KH;

    fused_features<<<dim3(16, 16, NS), 256, 0, stream>>>(z, w1, b1, w2, b2, cosw, g);
    dft_row<<<NS * CROP, 256, 0, stream>>>(g, zr, zi);
    dft_col_mul_inv<<<NS * KH, 256, 0, stream>>>(zr, zi, wf, br, bi);
    idft_row<<<NS * CROP, 256, 0, stream>>>(br, bi, out);
}

// Round 3
// 126.687 us; speedup vs baseline: 8.7601x; 3.0723x over previous
//
#include <hip/hip_runtime.h>
#include <math.h>

#define NS   16
#define CIN  3
#define CF   32
#define CROP 256
#define KH   129

typedef _Float16 half8  __attribute__((ext_vector_type(8)));
typedef _Float16 half4v __attribute__((ext_vector_type(4)));
typedef float    f32x4  __attribute__((ext_vector_type(4)));

// ---------------- LDS layout for fused_features (bytes) -------------------
#define X_OFF 0
#define W_OFF 21504
#define Z_OFF 39936
#define LDS_BYTES 44736

__device__ __forceinline__ int xaddr(int q, int s) {
    return X_OFF + (q << 6) + ((s ^ ((q >> 1) & 3)) << 4);
}

// ---------------------------------------------------------------------------
// prep kernel: w2 -> swizzled-LDS byte image (f16), w1 -> packed MFMA frags
// ---------------------------------------------------------------------------
__global__ __launch_bounds__(256)
void wprep(const float* __restrict__ w1, const float* __restrict__ w2,
           _Float16* __restrict__ w1pk, _Float16* __restrict__ w2lin)
{
    int e = blockIdx.x * 256 + threadIdx.x;
    if (e < 9216) {
        int co = e / 288;
        int r  = e - co * 288;
        int ci = r / 9, k9 = r - ci * 9;
        int dstB = (((k9 << 5) + co) << 6) + ((((ci >> 3) ^ ((co >> 1) & 3))) << 4)
                 + ((ci & 7) << 1);
        w2lin[dstB >> 1] = (_Float16)w2[e];
    } else if (e < 9216 + 128) {
        int t = e - 9216;                 // cg*64 + lane
        int cg = t >> 6, lane = t & 63;
        int co = cg * 16 + (lane & 15);
        #pragma unroll
        for (int j = 0; j < 8; ++j) {
            int k = ((lane >> 4) << 3) + j;
            w1pk[t * 8 + j] = (k < 27) ? (_Float16)w1[co * 27 + k] : (_Float16)0.f;
        }
    }
}

// ---------------------------------------------------------------------------
// twiddle tables, pre-packed in MFMA B-fragment order:
//   tbl[((ks*NT + nt)*64 + lane)*8 + j]  = T[ks*32 + (lane>>4)*8 + j][nt*16 + (lane&15)]
// split hi/lo f16 planes.
// ---------------------------------------------------------------------------
__global__ __launch_bounds__(256)
void twiddle_setup(_Float16* __restrict__ TAh, _Float16* __restrict__ TAl,
                   _Float16* __restrict__ G1h, _Float16* __restrict__ G1l,
                   _Float16* __restrict__ G2h, _Float16* __restrict__ G2l,
                   _Float16* __restrict__ G3h, _Float16* __restrict__ G3l,
                   _Float16* __restrict__ G4h, _Float16* __restrict__ G4l,
                   _Float16* __restrict__ TCh, _Float16* __restrict__ TCl)
{
    const float step = 6.28318530717958647692f / 256.0f;
    int e = blockIdx.x * 256 + threadIdx.x;

    if (e < 69632) {                      // TA: [K=256 x][N=272 c], 8 ks x 17 nt
        int j = e & 7, lane = (e >> 3) & 63, q = e >> 9;
        int nt = q % 17, ks = q / 17;
        int x = ks * 32 + ((lane >> 4) << 3) + j;
        int c = nt * 16 + (lane & 15);
        float v = 0.f;
        if (c <= 128)                    v =  cosf(step * (float)((x * c) & 255));
        else if (c >= 136 && c <= 264)   v = -sinf(step * (float)((x * (c - 136)) & 255));
        _Float16 h = (_Float16)v; TAh[e] = h; TAl[e] = (_Float16)(v - (float)h);
        return;
    }
    e -= 69632;
    if (e < 131072) {                     // G1..G4: [K=512 kk][N=256 m], 16 ks x 16 nt
        int j = e & 7, lane = (e >> 3) & 63, q = e >> 9;
        int nt = q & 15, ks = q >> 4;
        int kk = ks * 32 + ((lane >> 4) << 3) + j;
        int m  = nt * 16 + (lane & 15);
        int y = kk & 255, part = kk >> 8;
        float s, cv; __sincosf(step * (float)((y * m) & 255), &s, &cv);
        float g1 = part ? s  : cv;                       // [C; S]
        float g2 = part ? cv : -s;                       // [-S; C]
        float g3 = (part ? -s : cv) * (1.f / 256.f);     // [C;-S]/256
        float g4 = (part ? cv : s) * (1.f / 256.f);      // [S; C]/256
        _Float16 h;
        h = (_Float16)g1; G1h[e] = h; G1l[e] = (_Float16)(g1 - (float)h);
        h = (_Float16)g2; G2h[e] = h; G2l[e] = (_Float16)(g2 - (float)h);
        h = (_Float16)g3; G3h[e] = h; G3l[e] = (_Float16)(g3 - (float)h);
        h = (_Float16)g4; G4h[e] = h; G4l[e] = (_Float16)(g4 - (float)h);
        return;
    }
    e -= 131072;
    if (e < 73728) {                      // TC: [K=288 kk][N=256 x], 9 ks x 16 nt
        int j = e & 7, lane = (e >> 3) & 63, q = e >> 9;
        int nt = q & 15, ks = q >> 4;
        int kk = ks * 32 + ((lane >> 4) << 3) + j;
        int x  = nt * 16 + (lane & 15);
        int part = (kk >= 144) ? 1 : 0, k = kk - part * 144;
        float v = 0.f;
        if (k <= 128) {
            float w = (k == 0 || k == 128) ? 1.f : 2.f;
            float s, cv; __sincosf(step * (float)((k * x) & 255), &s, &cv);
            v = (part ? -w * s : w * cv) * (1.f / 256.f);
        }
        _Float16 h = (_Float16)v; TCh[e] = h; TCl[e] = (_Float16)(v - (float)h);
    }
}

// ---------------------------------------------------------------------------
// Kernel 1: fused conv1+ReLU -> conv2 -> LRN -> *cos_window -> channel sum
// outputs g split into hi/lo f16 planes [4096][256]
// ---------------------------------------------------------------------------
__global__ __launch_bounds__(256, 2)
void fused_features(const float* __restrict__ z,
                    const _Float16* __restrict__ w1pk,
                    const float* __restrict__ b1,
                    const _Float16* __restrict__ w2lin,
                    const float* __restrict__ b2,
                    const float* __restrict__ cosw,
                    _Float16* __restrict__ g2h, _Float16* __restrict__ g2l)
{
    __shared__ __align__(16) unsigned char smem[LDS_BYTES];
    float* ztile = (float*)(smem + Z_OFF);

    const int tid  = threadIdx.x;
    const int lane = tid & 63;
    const int wv   = tid >> 6;
    const int l15  = lane & 15;
    const int lhi  = lane >> 4;

    const int n  = blockIdx.z;
    const int bx = blockIdx.x, by = blockIdx.y;
    const int fy0 = by * 16 - 1;
    const int fx0 = bx * 16 - 1;

    // ---- stage z tile (3 x 20 x 20) + w2 image copy + w1 frags ----
    const int zy0 = by * 16 - 2;
    const int zx0 = bx * 16 - 2;
    for (int idx = tid; idx < CIN * 400; idx += 256) {
        int ci = idx / 400;
        int r  = idx - ci * 400;
        int yy = r / 20, xx = r - yy * 20;
        int gy = zy0 + yy, gx = zx0 + xx;
        float v = 0.0f;
        if ((unsigned)gy < CROP && (unsigned)gx < CROP)
            v = z[((n * CIN + ci) * CROP + gy) * CROP + gx];
        ztile[idx] = v;
    }
    {   // w2: pre-swizzled image, plain vector copy (1152 uint4)
        const uint4* w2v = (const uint4*)w2lin;
        #pragma unroll
        for (int i = 0; i < 4; ++i)
            *(uint4*)(smem + W_OFF + (tid + i * 256) * 16) = w2v[tid + i * 256];
        if (tid < 128)
            *(uint4*)(smem + W_OFF + (tid + 1024) * 16) = w2v[tid + 1024];
    }
    half8 w1f0 = *(const half8*)(w1pk + lane * 8);
    half8 w1f1 = *(const half8*)(w1pk + 512 + lane * 8);
    float bias1[2] = { b1[l15], b1[16 + l15] };
    float bias2[2] = { b2[l15], b2[16 + l15] };

    __syncthreads();

    // ---- im2col into X (writes only; w2 region untouched) ----
    for (int q = tid; q < 324; q += 256) {
        int y = q / 18, x = q - y * 18;
        const float* zb = ztile + y * 20 + x;
        _Float16 v[32];
        #pragma unroll
        for (int ci = 0; ci < 3; ++ci)
            #pragma unroll
            for (int ky = 0; ky < 3; ++ky)
                #pragma unroll
                for (int kx = 0; kx < 3; ++kx)
                    v[ci * 9 + ky * 3 + kx] = (_Float16)zb[ci * 400 + ky * 20 + kx];
        #pragma unroll
        for (int k = 27; k < 32; ++k) v[k] = (_Float16)0.f;
        #pragma unroll
        for (int s = 0; s < 4; ++s) {
            half8 h;
            #pragma unroll
            for (int j = 0; j < 8; ++j) h[j] = v[s * 8 + j];
            *(half8*)(smem + xaddr(q, s)) = h;
        }
    }
    __syncthreads();

    // ---- conv1 via MFMA, in place ----
    const f32x4 zero4 = {0.f, 0.f, 0.f, 0.f};
    for (int t = wv; t < 21; t += 4) {
        int qa = t * 16 + l15;
        half8 a = *(const half8*)(smem + xaddr(qa, lhi));
        f32x4 d0 = __builtin_amdgcn_mfma_f32_16x16x32_f16(a, w1f0, zero4, 0, 0, 0);
        f32x4 d1 = __builtin_amdgcn_mfma_f32_16x16x32_f16(a, w1f1, zero4, 0, 0, 0);
        #pragma unroll
        for (int r = 0; r < 4; ++r) {
            int qq = t * 16 + lhi * 4 + r;
            int y = qq / 18, x = qq - y * 18;
            int gy = fy0 + y, gx = fx0 + x;
            bool ok = ((unsigned)gy < CROP) && ((unsigned)gx < CROP) && (qq < 324);
            float v0 = ok ? fmaxf(d0[r] + bias1[0], 0.f) : 0.f;
            float v1 = ok ? fmaxf(d1[r] + bias1[1], 0.f) : 0.f;
            int sw = (qq >> 1) & 3;
            int c0 = l15, c1 = 16 + l15;
            *(_Float16*)(smem + X_OFF + (qq << 6) + (((c0 >> 3) ^ sw) << 4) + ((c0 & 7) << 1)) = (_Float16)v0;
            *(_Float16*)(smem + X_OFF + (qq << 6) + (((c1 >> 3) ^ sw) << 4) + ((c1 & 7) << 1)) = (_Float16)v1;
        }
    }
    __syncthreads();

    // ---- conv2 via MFMA: 9 shifted GEMMs, K=32 channels ----
    f32x4 acc[4][2];
    #pragma unroll
    for (int tt = 0; tt < 4; ++tt)
        #pragma unroll
        for (int cg = 0; cg < 2; ++cg)
            acc[tt][cg] = (f32x4){bias2[cg], bias2[cg], bias2[cg], bias2[cg]};

    #pragma unroll
    for (int k9 = 0; k9 < 9; ++k9) {
        const int ky = k9 / 3, kx = k9 - 3 * (k9 / 3);
        half8 bf0 = *(const half8*)(smem + W_OFF + (((k9 << 5) + l15) << 6)
                                    + ((lhi ^ ((l15 >> 1) & 3)) << 4));
        half8 bf1 = *(const half8*)(smem + W_OFF + (((k9 << 5) + l15 + 16) << 6)
                                    + ((lhi ^ (((l15 + 16) >> 1) & 3)) << 4));
        #pragma unroll
        for (int tt = 0; tt < 4; ++tt) {
            int py = wv * 4 + tt;
            int q  = (py + ky) * 18 + l15 + kx;
            half8 a = *(const half8*)(smem + xaddr(q, lhi));
            acc[tt][0] = __builtin_amdgcn_mfma_f32_16x16x32_f16(a, bf0, acc[tt][0], 0, 0, 0);
            acc[tt][1] = __builtin_amdgcn_mfma_f32_16x16x32_f16(a, bf1, acc[tt][1], 0, 0, 0);
        }
    }
    __syncthreads();

    // ---- dump to E [256][36] f32 ----
    float* E = (float*)smem;
    #pragma unroll
    for (int tt = 0; tt < 4; ++tt)
        #pragma unroll
        for (int cg = 0; cg < 2; ++cg)
            #pragma unroll
            for (int r = 0; r < 4; ++r) {
                int p  = (wv * 4 + tt) * 16 + lhi * 4 + r;
                int co = cg * 16 + l15;
                E[p * 36 + co] = acc[tt][cg][r];
            }
    __syncthreads();

    // ---- LRN (2nd-order Taylor; x<=2e-4 so error ~1e-11) + cosw + sum ----
    {
        const float* row = E + tid * 36;
        float a2[CF], sq[CF];
        #pragma unroll
        for (int c = 0; c < CF; ++c) { a2[c] = row[c]; sq[c] = a2[c] * a2[c]; }
        float win = sq[0] + sq[1] + sq[2];
        float s = 0.0f;
        #pragma unroll
        for (int c = 0; c < CF; ++c) {
            float t = 2e-5f * win;                      // alpha/size * win
            float f = fmaf(t, fmaf(t, 0.65625f, -0.75f), 1.0f);
            s = fmaf(a2[c], f, s);
            if (c + 3 < CF) win += sq[c + 3];
            if (c - 2 >= 0) win -= sq[c - 2];
        }
        const int ty = tid >> 4, tx = tid & 15;
        const int gy = by * 16 + ty, gx = bx * 16 + tx;
        float val = s * cosw[gy * CROP + gx];
        _Float16 h = (_Float16)val;
        int o = (n * CROP + gy) * CROP + gx;
        g2h[o] = h;
        g2l[o] = (_Float16)(val - (float)h);
    }
}

// ---------------------------------------------------------------------------
// Stage A: row rfft.  M=4096 (n,y), K=256 (x), N=272 (re0..128 | pad | im0..128)
// out: Zt[n*144 + k][part*256 + y]  (hi/lo planes, rows k>128 unused pads)
// ---------------------------------------------------------------------------
__global__ __launch_bounds__(256)
void fft_rows(const _Float16* __restrict__ g2h, const _Float16* __restrict__ g2l,
              const _Float16* __restrict__ TAh, const _Float16* __restrict__ TAl,
              _Float16* __restrict__ Zth, _Float16* __restrict__ Ztl)
{
    const int lane = threadIdx.x & 63;
    const int wu = blockIdx.x * 4 + (threadIdx.x >> 6);   // 0..1279
    const int mt = wu / 5;
    const int nt0 = (wu - mt * 5) * 4;
    const int l15 = lane & 15, lhi = lane >> 4;
    const int rowA = mt * 16 + l15;

    f32x4 acc[4] = {};
    for (int ks = 0; ks < 8; ++ks) {
        const int ao = rowA * 256 + ks * 32 + lhi * 8;
        half8 Ah = *(const half8*)(g2h + ao);
        half8 Al = *(const half8*)(g2l + ao);
        #pragma unroll
        for (int j = 0; j < 4; ++j) {
            int nt = nt0 + j;
            if (nt < 17) {
                const int bo = ((ks * 17 + nt) * 64 + lane) * 8;
                half8 Bh = *(const half8*)(TAh + bo);
                half8 Bl = *(const half8*)(TAl + bo);
                acc[j] = __builtin_amdgcn_mfma_f32_16x16x32_f16(Ah, Bh, acc[j], 0, 0, 0);
                acc[j] = __builtin_amdgcn_mfma_f32_16x16x32_f16(Ah, Bl, acc[j], 0, 0, 0);
                acc[j] = __builtin_amdgcn_mfma_f32_16x16x32_f16(Al, Bh, acc[j], 0, 0, 0);
            }
        }
    }
    const int rowD = mt * 16 + lhi * 4;
    const int n = rowD >> 8, y = rowD & 255;
    #pragma unroll
    for (int j = 0; j < 4; ++j) {
        int nt = nt0 + j;
        if (nt < 17) {
            int c = nt * 16 + l15;
            int row_k = -1, koff = 0;
            if (c <= 128)                  { row_k = c;       koff = 0;   }
            else if (c >= 136 && c <= 264) { row_k = c - 136; koff = 256; }
            if (row_k >= 0) {
                half4v hv, lv;
                #pragma unroll
                for (int r = 0; r < 4; ++r) {
                    float v = acc[j][r];
                    _Float16 h = (_Float16)v;
                    hv[r] = h; lv[r] = (_Float16)(v - (float)h);
                }
                size_t o = (size_t)(n * 144 + row_k) * 512 + koff + y;
                *(half4v*)(Zth + o) = hv;
                *(half4v*)(Ztl + o) = lv;
            }
        }
    }
}

// ---------------------------------------------------------------------------
// Stage B1: col fft + *conj(wf[0,1]).  M=2304 (n*144+k), K=512 ([Zre;Zim] y),
// N=256 (m). two planes via G1=[C;S], G2=[-S;C]. out P[n*144+k][part*256+m]
// ---------------------------------------------------------------------------
__global__ __launch_bounds__(256)
void fft_cols_mul(const _Float16* __restrict__ Zth, const _Float16* __restrict__ Ztl,
                  const _Float16* __restrict__ G1h, const _Float16* __restrict__ G1l,
                  const _Float16* __restrict__ G2h, const _Float16* __restrict__ G2l,
                  const float* __restrict__ wf,
                  _Float16* __restrict__ Ph, _Float16* __restrict__ Pl)
{
    const int lane = threadIdx.x & 63;
    const int wu = blockIdx.x * 4 + (threadIdx.x >> 6);   // 0..1151
    const int mt = wu >> 3;
    const int nt0 = (wu & 7) * 2;
    const int l15 = lane & 15, lhi = lane >> 4;
    const int rowA = mt * 16 + l15;

    f32x4 aR[2] = {}, aI[2] = {};
    for (int ks = 0; ks < 16; ++ks) {
        const int ao = rowA * 512 + ks * 32 + lhi * 8;
        half8 Ah = *(const half8*)(Zth + ao);
        half8 Al = *(const half8*)(Ztl + ao);
        #pragma unroll
        for (int j = 0; j < 2; ++j) {
            const int bo = ((ks * 16 + nt0 + j) * 64 + lane) * 8;
            half8 B1h = *(const half8*)(G1h + bo);
            half8 B1l = *(const half8*)(G1l + bo);
            half8 B2h = *(const half8*)(G2h + bo);
            half8 B2l = *(const half8*)(G2l + bo);
            aR[j] = __builtin_amdgcn_mfma_f32_16x16x32_f16(Ah, B1h, aR[j], 0, 0, 0);
            aR[j] = __builtin_amdgcn_mfma_f32_16x16x32_f16(Ah, B1l, aR[j], 0, 0, 0);
            aR[j] = __builtin_amdgcn_mfma_f32_16x16x32_f16(Al, B1h, aR[j], 0, 0, 0);
            aI[j] = __builtin_amdgcn_mfma_f32_16x16x32_f16(Ah, B2h, aI[j], 0, 0, 0);
            aI[j] = __builtin_amdgcn_mfma_f32_16x16x32_f16(Ah, B2l, aI[j], 0, 0, 0);
            aI[j] = __builtin_amdgcn_mfma_f32_16x16x32_f16(Al, B2h, aI[j], 0, 0, 0);
        }
    }
    const int kbase = (mt % 9) * 16 + lhi * 4;
    const int rowP0 = mt * 16 + lhi * 4;
    const float* wf1 = wf + 256 * 129 * 2;     // channel 1 slice
    #pragma unroll
    for (int j = 0; j < 2; ++j) {
        int m = (nt0 + j) * 16 + l15;
        #pragma unroll
        for (int r = 0; r < 4; ++r) {
            int k = kbase + r;
            float wr = wf1[(m * 129 + k) * 2 + 0];
            float wi = wf1[(m * 129 + k) * 2 + 1];
            float fr = aR[j][r], fi = aI[j][r];
            float pr = wr * fr + wi * fi;
            float pi = wr * fi - wi * fr;
            size_t o = (size_t)(rowP0 + r) * 512 + m;
            _Float16 h;
            h = (_Float16)pr; Ph[o] = h;       Pl[o] = (_Float16)(pr - (float)h);
            h = (_Float16)pi; Ph[o + 256] = h; Pl[o + 256] = (_Float16)(pi - (float)h);
        }
    }
}

// ---------------------------------------------------------------------------
// Stage B2: col ifft (1/256).  M=2304 (n*144+k), K=512 ([Pre;Pim] m), N=256 (y)
// G3=[C;-S]/256, G4=[S;C]/256.  out Bt[n*256+y][part*144+k]
// ---------------------------------------------------------------------------
__global__ __launch_bounds__(256)
void fft_cols_inv(const _Float16* __restrict__ Ph, const _Float16* __restrict__ Pl,
                  const _Float16* __restrict__ G3h, const _Float16* __restrict__ G3l,
                  const _Float16* __restrict__ G4h, const _Float16* __restrict__ G4l,
                  _Float16* __restrict__ Bth, _Float16* __restrict__ Btl)
{
    const int lane = threadIdx.x & 63;
    const int wu = blockIdx.x * 4 + (threadIdx.x >> 6);   // 0..1151
    const int mt = wu >> 3;
    const int nt0 = (wu & 7) * 2;
    const int l15 = lane & 15, lhi = lane >> 4;
    const int rowA = mt * 16 + l15;

    f32x4 aR[2] = {}, aI[2] = {};
    for (int ks = 0; ks < 16; ++ks) {
        const int ao = rowA * 512 + ks * 32 + lhi * 8;
        half8 Ah = *(const half8*)(Ph + ao);
        half8 Al = *(const half8*)(Pl + ao);
        #pragma unroll
        for (int j = 0; j < 2; ++j) {
            const int bo = ((ks * 16 + nt0 + j) * 64 + lane) * 8;
            half8 B3h = *(const half8*)(G3h + bo);
            half8 B3l = *(const half8*)(G3l + bo);
            half8 B4h = *(const half8*)(G4h + bo);
            half8 B4l = *(const half8*)(G4l + bo);
            aR[j] = __builtin_amdgcn_mfma_f32_16x16x32_f16(Ah, B3h, aR[j], 0, 0, 0);
            aR[j] = __builtin_amdgcn_mfma_f32_16x16x32_f16(Ah, B3l, aR[j], 0, 0, 0);
            aR[j] = __builtin_amdgcn_mfma_f32_16x16x32_f16(Al, B3h, aR[j], 0, 0, 0);
            aI[j] = __builtin_amdgcn_mfma_f32_16x16x32_f16(Ah, B4h, aI[j], 0, 0, 0);
            aI[j] = __builtin_amdgcn_mfma_f32_16x16x32_f16(Ah, B4l, aI[j], 0, 0, 0);
            aI[j] = __builtin_amdgcn_mfma_f32_16x16x32_f16(Al, B4h, aI[j], 0, 0, 0);
        }
    }
    const int n = mt / 9;
    const int kbase = (mt % 9) * 16 + lhi * 4;
    #pragma unroll
    for (int j = 0; j < 2; ++j) {
        int y = (nt0 + j) * 16 + l15;
        size_t base = (size_t)(n * 256 + y) * 288;
        half4v hv0, lv0, hv1, lv1;
        #pragma unroll
        for (int r = 0; r < 4; ++r) {
            float v = aR[j][r]; _Float16 h = (_Float16)v;
            hv0[r] = h; lv0[r] = (_Float16)(v - (float)h);
            float v2 = aI[j][r]; _Float16 h2 = (_Float16)v2;
            hv1[r] = h2; lv1[r] = (_Float16)(v2 - (float)h2);
        }
        *(half4v*)(Bth + base + kbase) = hv0;
        *(half4v*)(Btl + base + kbase) = lv0;
        *(half4v*)(Bth + base + 144 + kbase) = hv1;
        *(half4v*)(Btl + base + 144 + kbase) = lv1;
    }
}

// ---------------------------------------------------------------------------
// Stage C: row irfft (1/256).  M=4096 (n,y), K=288 ([Bre;Bim] k), N=256 (x)
// writes final response f32
// ---------------------------------------------------------------------------
__global__ __launch_bounds__(256)
void irfft_rows(const _Float16* __restrict__ Bth, const _Float16* __restrict__ Btl,
                const _Float16* __restrict__ TCh, const _Float16* __restrict__ TCl,
                float* __restrict__ out)
{
    const int lane = threadIdx.x & 63;
    const int wu = blockIdx.x * 4 + (threadIdx.x >> 6);   // 0..1023
    const int mt = wu >> 2;
    const int nt0 = (wu & 3) * 4;
    const int l15 = lane & 15, lhi = lane >> 4;
    const int rowA = mt * 16 + l15;

    f32x4 acc[4] = {};
    for (int ks = 0; ks < 9; ++ks) {
        const int ao = rowA * 288 + ks * 32 + lhi * 8;
        half8 Ah = *(const half8*)(Bth + ao);
        half8 Al = *(const half8*)(Btl + ao);
        #pragma unroll
        for (int j = 0; j < 4; ++j) {
            const int bo = ((ks * 16 + nt0 + j) * 64 + lane) * 8;
            half8 Bh = *(const half8*)(TCh + bo);
            half8 Bl = *(const half8*)(TCl + bo);
            acc[j] = __builtin_amdgcn_mfma_f32_16x16x32_f16(Ah, Bh, acc[j], 0, 0, 0);
            acc[j] = __builtin_amdgcn_mfma_f32_16x16x32_f16(Ah, Bl, acc[j], 0, 0, 0);
            acc[j] = __builtin_amdgcn_mfma_f32_16x16x32_f16(Al, Bh, acc[j], 0, 0, 0);
        }
    }
    const int rowD = mt * 16 + lhi * 4;
    #pragma unroll
    for (int j = 0; j < 4; ++j) {
        int x = (nt0 + j) * 16 + l15;
        #pragma unroll
        for (int r = 0; r < 4; ++r)
            out[(size_t)(rowD + r) * 256 + x] = acc[j][r];
    }
}

// ---------------------------------------------------------------------------
extern "C" void kernel_launch(void* const* d_in, const int* in_sizes, int n_in,
                              void* d_out, int out_size, void* d_ws, size_t ws_size,
                              hipStream_t stream)
{
    const float* z    = (const float*)d_in[0];
    const float* w1   = (const float*)d_in[1];
    const float* b1   = (const float*)d_in[2];
    const float* w2   = (const float*)d_in[3];
    const float* b2   = (const float*)d_in[4];
    const float* cosw = (const float*)d_in[5];
    const float* wf   = (const float*)d_in[6];
    float* out = (float*)d_out;

    // ---- workspace carve-up (aligned 256B) ----
    char* p = (char*)d_ws;
    auto take = [&](size_t bytes) {
        char* r = p; p += (bytes + 255) & ~(size_t)255; return r;
    };
    _Float16* g2h = (_Float16*)take(4096 * 256 * 2);
    _Float16* g2l = (_Float16*)take(4096 * 256 * 2);
    _Float16* Zth = (_Float16*)take(2304 * 512 * 2);
    _Float16* Ztl = (_Float16*)take(2304 * 512 * 2);
    _Float16* Ph  = (_Float16*)take(2304 * 512 * 2);
    _Float16* Pl  = (_Float16*)take(2304 * 512 * 2);
    _Float16* TAh = (_Float16*)take(69632 * 2);
    _Float16* TAl = (_Float16*)take(69632 * 2);
    _Float16* G1h = (_Float16*)take(131072 * 2);
    _Float16* G1l = (_Float16*)take(131072 * 2);
    _Float16* G2h = (_Float16*)take(131072 * 2);
    _Float16* G2l = (_Float16*)take(131072 * 2);
    _Float16* G3h = (_Float16*)take(131072 * 2);
    _Float16* G3l = (_Float16*)take(131072 * 2);
    _Float16* G4h = (_Float16*)take(131072 * 2);
    _Float16* G4l = (_Float16*)take(131072 * 2);
    _Float16* TCh = (_Float16*)take(73728 * 2);
    _Float16* TCl = (_Float16*)take(73728 * 2);
    _Float16* w1pk  = (_Float16*)take(1024 * 2);
    _Float16* w2lin = (_Float16*)take(9216 * 2);
    // Bt aliases Zt (dead after B1; same size 2304*512 == 4096*288)
    _Float16* Bth = Zth;
    _Float16* Btl = Ztl;

    wprep<<<37, 256, 0, stream>>>(w1, w2, w1pk, w2lin);
    twiddle_setup<<<1072, 256, 0, stream>>>(TAh, TAl, G1h, G1l, G2h, G2l,
                                            G3h, G3l, G4h, G4l, TCh, TCl);
    fused_features<<<dim3(16, 16, NS), 256, 0, stream>>>(z, w1pk, b1, w2lin, b2,
                                                         cosw, g2h, g2l);
    fft_rows<<<320, 256, 0, stream>>>(g2h, g2l, TAh, TAl, Zth, Ztl);
    fft_cols_mul<<<288, 256, 0, stream>>>(Zth, Ztl, G1h, G1l, G2h, G2l, wf, Ph, Pl);
    fft_cols_inv<<<288, 256, 0, stream>>>(Ph, Pl, G3h, G3l, G4h, G4l, Bth, Btl);
    irfft_rows<<<256, 256, 0, stream>>>(Bth, Btl, TCh, TCl, out);
}